// Round 4
// baseline (374.936 us; speedup 1.0000x reference)
//
#include <hip/hip_runtime.h>
#include <math.h>

namespace {

constexpr int B_ = 256;
constexpr int R_ = 1152;
constexpr int C_ = 10;
constexpr int O_ = 16;
constexpr int I_ = 8;
constexpr int CO_ = C_ * O_;          // 160
constexpr int WRI_ = C_ * O_ * I_;    // 1280 floats of W per route

constexpr int KS_  = 32;              // r-splits in s-phase
constexpr int RC_  = R_ / KS_;        // 36 routes per s-block
constexpr int RT_  = 2;               // routes per a-block -> 576 blocks
constexpr int NA_  = R_ / RT_;        // 576 a-blocks
constexpr int VSEG_ = 8;              // b-segments in v-phase -> 1280 blocks

// fallback tier-3 params
constexpr int KSF_ = 16;
constexpr int RCF_ = R_ / KSF_;       // 72
constexpr int MBF_ = 16;

// ws layout (float offsets)
constexpr size_t XT_OFF    = 0;                          // [R][B][I]
constexpr size_t XT_N      = (size_t)R_ * B_ * I_;       // 2,359,296
constexpr size_t SP_OFF    = XT_OFF + XT_N;              // [CO][KS][B]
constexpr size_t SP_N      = (size_t)CO_ * KS_ * B_;     // 1,310,720
constexpr size_t V_OFF     = SP_OFF + SP_N;              // [B][CO]
constexpr size_t V_N       = (size_t)B_ * CO_;           // 40,960
constexpr size_t BIJ_OFF   = V_OFF + V_N;                // [C][R]
constexpr size_t BIJ_N     = (size_t)C_ * R_;            // 11,520
constexpr size_t CIJ_OFF   = BIJ_OFF + BIJ_N;            // [C][R]
constexpr size_t CIJ_N     = (size_t)C_ * R_;
constexpr size_t CNT_OFF   = CIJ_OFF + CIJ_N;            // 1 counter
constexpr size_t FL_TOTAL  = CNT_OFF + 4;

__device__ __forceinline__ float squashf(float s) {
    // faithful to reference: s^2*s/((1+s^2)*sqrt(s^2)) == s*|s|/(1+s^2)
    return s * fabsf(s) / (1.0f + s * s);
}

// ===========================================================================
// k_tr2: x[b,r,i] -> xT[r,b,i] (+ zero bijT + zero a-phase counter).
// tile 8 b x 32 r.  grid 1152.
// ===========================================================================
__global__ __launch_bounds__(256) void k_tr2(const float* __restrict__ x,
                                             float* __restrict__ xT,
                                             float* __restrict__ bijT,
                                             unsigned* __restrict__ cnt) {
    __shared__ float t[8][32][8];
    const int tid = threadIdx.x;
    if (blockIdx.x == 0 && tid == 0) *cnt = 0u;
    {
        const int gi = blockIdx.x * 256 + tid;
        if (gi < C_ * R_) bijT[gi] = 0.f;
    }
    const int r0 = (blockIdx.x % 36) * 32;
    const int b0 = (blockIdx.x / 36) * 8;
    {
        const int rl = tid & 31, bl = tid >> 5;
        const float4* p = (const float4*)(x + ((size_t)(b0 + bl) * R_ + (r0 + rl)) * I_);
        const float4 a0 = p[0], a1 = p[1];
        float* d = &t[bl][rl][0];
        *(float4*)d = a0;
        *(float4*)(d + 4) = a1;
    }
    __syncthreads();
    {
        const int f = tid & 7, rw = tid >> 3;   // f = b-local
        const float* s8 = &t[f][rw][0];
        const float4 a0 = *(const float4*)s8, a1 = *(const float4*)(s8 + 4);
        float* d = xT + ((size_t)(r0 + rw) * B_ + (b0 + f)) * I_;
        *(float4*)d = a0;
        *(float4*)(d + 4) = a1;
    }
}

// ===========================================================================
// k_s6: spart[c*O+o, ks, b] = sum_{r in chunk} cw[r,c]*dot(W[r,c,o,:], xT[r,b,:])
// 1-D grid 1280: bid = c*128 + chunk, chunk = ks*4 + bq.
// XCD-aware decomposition: c-stride is 128 == 0 (mod 8), so all 10 c-copies
// of an x-chunk share bid%8 -> land on the SAME XCD (round-robin dispatch)
// -> x-chunk fetched from L3 once, L2-hit for the other 9 capsules.
// (was: grid (c,ks,bq) -> the 10 c-copies sprayed across XCDs -> ~94 MB
//  beyond-L2 x traffic per launch, ~10x the unique 9.4 MB.)
// 256 thr = 4 o-waves x 64 b lanes; W chunk (36 r x 128) staged in LDS with
// cw folded in (18.4 KB -> still 8 blocks/CU by LDS); x read from global.
// ===========================================================================
template <bool UNIFORM>
__global__ __launch_bounds__(256) void k_s6(const float* __restrict__ xT,
                                            const float* __restrict__ Wm,
                                            const float* __restrict__ cijT,
                                            float* __restrict__ spart) {
    __shared__ __align__(16) float wl[RC_ * 128];   // 18.4 KB
    __shared__ float cwch[RC_];

    const int tid   = threadIdx.x;
    const int lane  = tid & 63;
    const int bid   = blockIdx.x;
    const int c     = bid >> 7;           // 0..9
    const int chunk = bid & 127;
    const int ks    = chunk >> 2;         // 0..31
    const int bq    = chunk & 3;          // 0..3
    const int r0    = ks * RC_;

    if (!UNIFORM) {
        if (tid < RC_) cwch[tid] = cijT[(size_t)c * R_ + r0 + tid];
        __syncthreads();
    }

    // stage cw-scaled W chunk: 36 r x 32 f4 = 1152 f4
    {
        const float4* src = (const float4*)(Wm + ((size_t)r0 * C_ + c) * 128);
        float4* dst = (float4*)wl;
        #pragma unroll
        for (int k = 0; k < (RC_ * 32 + 255) / 256; ++k) {
            const int idx = tid + 256 * k;
            if (idx < RC_ * 32) {
                const int r = idx >> 5, q = idx & 31;
                float4 wv = src[(size_t)r * (C_ * 32) + q];
                const float cw = UNIFORM ? (1.0f / (float)R_) : cwch[r];
                wv.x *= cw; wv.y *= cw; wv.z *= cw; wv.w *= cw;
                dst[idx] = wv;
            }
        }
    }
    __syncthreads();

    const int o0 = (tid >> 6) * 4;        // wave-uniform -> LDS broadcast reads
    const float* xbase = xT + ((size_t)r0 * B_ + bq * 64 + lane) * I_;

    float acc[4] = {0.f, 0.f, 0.f, 0.f};

    #pragma unroll 4
    for (int r = 0; r < RC_; ++r) {
        const float4* xp = (const float4*)(xbase + (size_t)r * B_ * I_);
        const float4 a0 = xp[0], a1 = xp[1];
        const float4* wp = (const float4*)&wl[r * 128 + o0 * 8];
        #pragma unroll
        for (int oo = 0; oo < 4; ++oo) {
            const float4 w0 = wp[oo * 2 + 0];
            const float4 w1 = wp[oo * 2 + 1];
            float a = acc[oo];
            a = fmaf(a0.x, w0.x, a);
            a = fmaf(a0.y, w0.y, a);
            a = fmaf(a0.z, w0.z, a);
            a = fmaf(a0.w, w0.w, a);
            a = fmaf(a1.x, w1.x, a);
            a = fmaf(a1.y, w1.y, a);
            a = fmaf(a1.z, w1.z, a);
            a = fmaf(a1.w, w1.w, a);
            acc[oo] = a;
        }
    }

    float* sp = spart + (((size_t)(c * O_ + o0)) * KS_ + ks) * B_ + bq * 64 + lane;
    #pragma unroll
    for (int oo = 0; oo < 4; ++oo)
        sp[(size_t)oo * KS_ * B_] = acc[oo];
}

// ===========================================================================
// k_v4: dest[b,co] = squash(sum_ks spart[co,ks,b]).  grid 1280 (co x 8 bsegs
// of 32 b), 256 thr = 8 ks-groups x 32 b; each thread sums 4 partials.
// ===========================================================================
__global__ __launch_bounds__(256) void k_v4(const float* __restrict__ spart,
                                            float* __restrict__ dest) {
    __shared__ float sh[7 * 32];
    const int tid  = threadIdx.x;
    const int bl   = tid & 31;
    const int g    = tid >> 5;            // 0..7
    const int co2  = blockIdx.x % CO_;
    const int bseg = blockIdx.x / CO_;    // 0..7
    const float* p = spart + (((size_t)co2) * KS_ + g * 4) * B_ + bseg * 32 + bl;
    float t0 = 0.f, t1 = 0.f;
    #pragma unroll
    for (int j = 0; j < 4; j += 2) {
        t0 += p[(size_t)(j + 0) * B_];
        t1 += p[(size_t)(j + 1) * B_];
    }
    const float s = t0 + t1;
    if (g) sh[(g - 1) * 32 + bl] = s;
    __syncthreads();
    if (g == 0) {
        float tot = s;
        #pragma unroll
        for (int k = 0; k < 7; ++k) tot += sh[k * 32 + bl];
        const int b = bseg * 32 + bl;
        dest[(size_t)b * CO_ + co2] = squashf(tot);
    }
}

// ===========================================================================
// k_a5: bijT[c, r0+rr] += (1/B) sum_o sum_i W[r,c,o,i]*(sum_b v[b,c,o]*xT[r,b,i])
// grid 576 blocks, 640 thr = 160 co x 4 b-groups of 64.
// bijT updates via device atomicAdd; the LAST block (atomic counter) then
// computes softmax(bijT) -> cijT in-kernel (10 waves = 10 capsules),
// replacing the separate k_cw launch.  Counter self-resets for next iter.
// ===========================================================================
__global__ __launch_bounds__(640) void k_a5(const float* __restrict__ xT,
                                            const float* __restrict__ Wm,
                                            const float* __restrict__ v,
                                            float* __restrict__ bijT,
                                            float* __restrict__ cijT,
                                            unsigned* __restrict__ cnt) {
    __shared__ __align__(16) float xrow[RT_ * B_ * I_];   // 16 KB
    __shared__ float part[RT_][640];
    __shared__ unsigned islast;

    const int tid = threadIdx.x;
    const int r0  = blockIdx.x * RT_;

    for (int k = tid; k < RT_ * B_ * I_ / 4; k += 640)
        ((float4*)xrow)[k] = ((const float4*)(xT + (size_t)r0 * B_ * I_))[k];
    __syncthreads();

    const int co = tid % CO_;
    const int bg = tid / CO_;
    const int b0 = bg * 64;

    float acc[RT_][8];
    #pragma unroll
    for (int rr = 0; rr < RT_; ++rr)
        #pragma unroll
        for (int i = 0; i < 8; ++i) acc[rr][i] = 0.f;

    const float* vp = v + co;
    #pragma unroll 2
    for (int bb = 0; bb < 64; ++bb) {
        const int b = b0 + bb;
        const float vt = vp[(size_t)b * CO_];
        #pragma unroll
        for (int rr = 0; rr < RT_; ++rr) {
            const float4 y0 = *(const float4*)(&xrow[(rr * B_ + b) * I_]);
            const float4 y1 = *(const float4*)(&xrow[(rr * B_ + b) * I_ + 4]);
            acc[rr][0] = fmaf(vt, y0.x, acc[rr][0]);
            acc[rr][1] = fmaf(vt, y0.y, acc[rr][1]);
            acc[rr][2] = fmaf(vt, y0.z, acc[rr][2]);
            acc[rr][3] = fmaf(vt, y0.w, acc[rr][3]);
            acc[rr][4] = fmaf(vt, y1.x, acc[rr][4]);
            acc[rr][5] = fmaf(vt, y1.y, acc[rr][5]);
            acc[rr][6] = fmaf(vt, y1.z, acc[rr][6]);
            acc[rr][7] = fmaf(vt, y1.w, acc[rr][7]);
        }
    }

    #pragma unroll
    for (int rr = 0; rr < RT_; ++rr) {
        const float* wp = Wm + (((size_t)(r0 + rr)) * CO_ + co) * I_;
        const float4 w0 = *(const float4*)wp;
        const float4 w1 = *(const float4*)(wp + 4);
        const float p0 = fmaf(acc[rr][1], w0.y, acc[rr][0] * w0.x);
        const float p1 = fmaf(acc[rr][3], w0.w, acc[rr][2] * w0.z);
        const float p2 = fmaf(acc[rr][5], w1.y, acc[rr][4] * w1.x);
        const float p3 = fmaf(acc[rr][7], w1.w, acc[rr][6] * w1.z);
        part[rr][tid] = (p0 + p1) + (p2 + p3);
    }
    __syncthreads();

    if (tid < CO_) {
        #pragma unroll
        for (int rr = 0; rr < RT_; ++rr) {
            float a = part[rr][tid] + part[rr][CO_ + tid] +
                      part[rr][2 * CO_ + tid] + part[rr][3 * CO_ + tid];
            #pragma unroll
            for (int off = 8; off > 0; off >>= 1)
                a += __shfl_down(a, off, 16);
            if ((tid & 15) == 0)
                atomicAdd(&bijT[(size_t)(tid >> 4) * R_ + (r0 + rr)],
                          a * (1.0f / (float)B_));
        }
    }

    // ---- last-block softmax(bijT) -> cijT ----
    __threadfence();
    __syncthreads();
    if (tid == 0) {
        const unsigned old = atomicAdd(cnt, 1u);
        const unsigned il = (old == (unsigned)(NA_ - 1)) ? 1u : 0u;
        if (il) atomicExch(cnt, 0u);      // reset for next a-launch
        islast = il;
    }
    __syncthreads();
    if (islast) {
        const int wid  = tid >> 6;        // 0..9 = capsule
        const int lane = tid & 63;
        float* bp = bijT + (size_t)wid * R_;
        float bv[18];
        float m = -1e30f;
        #pragma unroll
        for (int j = 0; j < 18; ++j) {
            // atomic read: coherent view of other blocks' atomicAdds
            bv[j] = atomicAdd(bp + lane + 64 * j, 0.0f);
            m = fmaxf(m, bv[j]);
        }
        #pragma unroll
        for (int off = 32; off > 0; off >>= 1)
            m = fmaxf(m, __shfl_down(m, off, 64));
        m = __shfl(m, 0, 64);
        float se = 0.f;
        #pragma unroll
        for (int j = 0; j < 18; ++j) se += expf(bv[j] - m);
        #pragma unroll
        for (int off = 32; off > 0; off >>= 1)
            se += __shfl_down(se, off, 64);
        se = __shfl(se, 0, 64);
        const float inv = 1.0f / se;
        #pragma unroll
        for (int j = 0; j < 18; ++j)
            cijT[(size_t)wid * R_ + lane + 64 * j] = expf(bv[j] - m) * inv;
    }
}

// ===========================================================================
// FALLBACK tier 3 (tiny ws)
// ===========================================================================
template <bool UNIFORM>
__global__ __launch_bounds__(256) void k_s_f(const float* __restrict__ x,
                                             const float* __restrict__ Wm,
                                             const float* __restrict__ cij,
                                             float* __restrict__ s_out) {
    const int o  = threadIdx.x & 15;
    const int tb = threadIdx.x >> 4;
    const int b  = blockIdx.z * MBF_ + tb;
    const int c  = blockIdx.y;
    const int r0 = blockIdx.x * RCF_;

    const float* xp = x + ((size_t)b * R_ + r0) * I_;
    const float* wp = Wm + (((size_t)r0 * C_ + c) * O_ + o) * I_;
    const float* cp = cij + (size_t)r0 * C_ + c;

    float acc = 0.f;
    #pragma unroll 4
    for (int r = 0; r < RCF_; ++r) {
        const float4 xv0 = *(const float4*)(xp);
        const float4 xv1 = *(const float4*)(xp + 4);
        const float4 wv0 = *(const float4*)(wp);
        const float4 wv1 = *(const float4*)(wp + 4);
        const float p0 = fmaf(xv0.y, wv0.y, xv0.x * wv0.x);
        const float p1 = fmaf(xv0.w, wv0.w, xv0.z * wv0.z);
        const float p2 = fmaf(xv1.y, wv1.y, xv1.x * wv1.x);
        const float p3 = fmaf(xv1.w, wv1.w, xv1.z * wv1.z);
        const float cw = UNIFORM ? (1.0f / (float)R_) : cp[0];
        acc = fmaf(cw, (p0 + p1) + (p2 + p3), acc);
        xp += I_;
        wp += WRI_;
        cp += C_;
    }
    atomicAdd(&s_out[((size_t)b * C_ + c) * O_ + o], acc);
}

__global__ __launch_bounds__(256) void k_a_f(const float* __restrict__ x,
                                             const float* __restrict__ Wm,
                                             const float* __restrict__ s_in,
                                             float* __restrict__ amean) {
    __shared__ __align__(16) float wlds[2 * WRI_];
    __shared__ float red[4][2 * C_];

    const int tid = threadIdx.x;
    const int r0  = blockIdx.x * 2;

    const float* wsrc = Wm + (size_t)r0 * WRI_;
    #pragma unroll
    for (int k = 0; k < 2 * WRI_ / 256; ++k)
        wlds[tid + 256 * k] = wsrc[tid + 256 * k];
    __syncthreads();

    const int b    = tid;
    const int lane = tid & 63;
    const int wv   = tid >> 6;

    float xv[2][I_];
    const float4* xp4 = (const float4*)(x + ((size_t)b * R_ + r0) * I_);
    #pragma unroll
    for (int rr = 0; rr < 2; ++rr) {
        const float4 a0 = xp4[rr * 2 + 0];
        const float4 a1 = xp4[rr * 2 + 1];
        xv[rr][0] = a0.x; xv[rr][1] = a0.y; xv[rr][2] = a0.z; xv[rr][3] = a0.w;
        xv[rr][4] = a1.x; xv[rr][5] = a1.y; xv[rr][6] = a1.z; xv[rr][7] = a1.w;
    }

    #pragma unroll 1
    for (int c = 0; c < C_; ++c) {
        const float4* sp4 = (const float4*)(s_in + ((size_t)b * C_ + c) * O_);
        float v[O_];
        #pragma unroll
        for (int q = 0; q < 4; ++q) {
            const float4 sv = sp4[q];
            v[q * 4 + 0] = squashf(sv.x);
            v[q * 4 + 1] = squashf(sv.y);
            v[q * 4 + 2] = squashf(sv.z);
            v[q * 4 + 3] = squashf(sv.w);
        }
        #pragma unroll 1
        for (int rr = 0; rr < 2; ++rr) {
            const float4* wl4 = (const float4*)&wlds[(rr * C_ + c) * O_ * I_];
            float a = 0.f;
            #pragma unroll
            for (int o = 0; o < O_; ++o) {
                const float4 w0 = wl4[o * 2 + 0];
                const float4 w1 = wl4[o * 2 + 1];
                float u = xv[rr][0] * w0.x;
                u = fmaf(xv[rr][1], w0.y, u);
                u = fmaf(xv[rr][2], w0.z, u);
                u = fmaf(xv[rr][3], w0.w, u);
                u = fmaf(xv[rr][4], w1.x, u);
                u = fmaf(xv[rr][5], w1.y, u);
                u = fmaf(xv[rr][6], w1.z, u);
                u = fmaf(xv[rr][7], w1.w, u);
                a = fmaf(u, v[o], a);
            }
            #pragma unroll
            for (int off = 32; off > 0; off >>= 1)
                a += __shfl_down(a, off, 64);
            if (lane == 0) red[wv][rr * C_ + c] = a;
        }
    }

    __syncthreads();
    if (tid < 2 * C_) {
        const float t = red[0][tid] + red[1][tid] + red[2][tid] + red[3][tid];
        const int rr = tid / C_;
        const int c  = tid % C_;
        amean[(size_t)(r0 + rr) * C_ + c] = t * (1.0f / (float)B_);
    }
}

__global__ __launch_bounds__(256) void k_soft(const float* __restrict__ amean,
                                              float* __restrict__ bij,
                                              float* __restrict__ cij) {
    const int c   = blockIdx.x;
    const int tid = threadIdx.x;
    __shared__ float sred[4];

    float vals[5];
    float m = -1e30f;
    #pragma unroll
    for (int k = 0; k < 5; ++k) {
        const int r = tid + 256 * k;
        if (r < R_) {
            const size_t idx = (size_t)r * C_ + c;
            const float vv = bij[idx] + amean[idx];
            bij[idx] = vv;
            vals[k] = vv;
            m = fmaxf(m, vv);
        } else {
            vals[k] = -1e30f;
        }
    }
    #pragma unroll
    for (int off = 32; off > 0; off >>= 1)
        m = fmaxf(m, __shfl_down(m, off, 64));
    if ((tid & 63) == 0) sred[tid >> 6] = m;
    __syncthreads();
    const float bm = fmaxf(fmaxf(sred[0], sred[1]), fmaxf(sred[2], sred[3]));
    __syncthreads();

    float se = 0.f;
    #pragma unroll
    for (int k = 0; k < 5; ++k)
        se += (vals[k] > -1e29f) ? expf(vals[k] - bm) : 0.f;
    #pragma unroll
    for (int off = 32; off > 0; off >>= 1)
        se += __shfl_down(se, off, 64);
    if ((tid & 63) == 0) sred[tid >> 6] = se;
    __syncthreads();
    const float inv = 1.0f / (sred[0] + sred[1] + sred[2] + sred[3]);

    #pragma unroll
    for (int k = 0; k < 5; ++k) {
        const int r = tid + 256 * k;
        if (r < R_) cij[(size_t)r * C_ + c] = expf(vals[k] - bm) * inv;
    }
}

__global__ __launch_bounds__(256) void k_squash(float* __restrict__ s) {
    const int idx = blockIdx.x * 256 + threadIdx.x;
    if (idx < B_ * CO_) s[idx] = squashf(s[idx]);
}

} // namespace

extern "C" void kernel_launch(void* const* d_in, const int* in_sizes, int n_in,
                              void* d_out, int out_size, void* d_ws, size_t ws_size,
                              hipStream_t stream) {
    const float* x  = (const float*)d_in[0];   // [256,1152,8]
    const float* Wm = (const float*)d_in[1];   // [1152,10,16,8]
    float* out = (float*)d_out;                // [256,10,16] flat = 40960
    float* ws  = (float*)d_ws;

    const size_t need = FL_TOTAL * sizeof(float);

    if (ws_size >= need) {
        // ---------------- main path: 9 nodes ----------------
        float* xT    = ws + XT_OFF;
        float* spart = ws + SP_OFF;
        float* v     = ws + V_OFF;
        float* bijT  = ws + BIJ_OFF;
        float* cijT  = ws + CIJ_OFF;
        unsigned* cnt = (unsigned*)(ws + CNT_OFF);

        k_tr2<<<1152, 256, 0, stream>>>(x, xT, bijT, cnt);

        // iter 0 (uniform weights; softmax(0) == 1/R)
        k_s6<true><<<C_ * 128, 256, 0, stream>>>(xT, Wm, cijT, spart);
        k_v4<<<CO_ * VSEG_, 256, 0, stream>>>(spart, v);
        k_a5<<<NA_, 640, 0, stream>>>(xT, Wm, v, bijT, cijT, cnt);

        // iter 1
        k_s6<false><<<C_ * 128, 256, 0, stream>>>(xT, Wm, cijT, spart);
        k_v4<<<CO_ * VSEG_, 256, 0, stream>>>(spart, v);
        k_a5<<<NA_, 640, 0, stream>>>(xT, Wm, v, bijT, cijT, cnt);

        // iter 2: final v straight into d_out
        k_s6<false><<<C_ * 128, 256, 0, stream>>>(xT, Wm, cijT, spart);
        k_v4<<<CO_ * VSEG_, 256, 0, stream>>>(spart, out);
    } else {
        // ---------------- tier 3 ----------------
        float* s_buf = ws;
        float* cij   = ws + 40960;
        float* bij   = cij + R_ * C_;
        float* amean = bij + R_ * C_;

        const dim3 gsf(KSF_, C_, B_ / MBF_);

        hipMemsetAsync(bij, 0, R_ * C_ * sizeof(float), stream);

        hipMemsetAsync(s_buf, 0, B_ * CO_ * sizeof(float), stream);
        k_s_f<true><<<gsf, 256, 0, stream>>>(x, Wm, cij, s_buf);
        k_a_f<<<R_ / 2, 256, 0, stream>>>(x, Wm, s_buf, amean);
        k_soft<<<C_, 256, 0, stream>>>(amean, bij, cij);

        hipMemsetAsync(s_buf, 0, B_ * CO_ * sizeof(float), stream);
        k_s_f<false><<<gsf, 256, 0, stream>>>(x, Wm, cij, s_buf);
        k_a_f<<<R_ / 2, 256, 0, stream>>>(x, Wm, s_buf, amean);
        k_soft<<<C_, 256, 0, stream>>>(amean, bij, cij);

        hipMemsetAsync(out, 0, B_ * CO_ * sizeof(float), stream);
        k_s_f<false><<<gsf, 256, 0, stream>>>(x, Wm, cij, out);
        k_squash<<<(B_ * CO_ + 255) / 256, 256, 0, stream>>>(out);
    }
}

// Round 6
// 219.143 us; speedup vs baseline: 1.7109x; 1.7109x over previous
//
#include <hip/hip_runtime.h>
#include <math.h>

namespace {

constexpr int B_ = 256;
constexpr int R_ = 1152;
constexpr int C_ = 10;
constexpr int O_ = 16;
constexpr int I_ = 8;
constexpr int CO_ = C_ * O_;          // 160
constexpr int WRI_ = C_ * O_ * I_;    // 1280 floats of W per route

constexpr int KS_  = 32;              // r-splits in s-phase
constexpr int RC_  = R_ / KS_;        // 36 routes per s-block
constexpr int RT_  = 2;               // routes per a-block -> 576 blocks
constexpr int NA_  = R_ / RT_;        // 576 a-blocks

// fallback tier-3 params
constexpr int KSF_ = 16;
constexpr int RCF_ = R_ / KSF_;       // 72
constexpr int MBF_ = 16;

// ws layout (float offsets) — sA|sB|bij contiguous so k_tr zeroes one range
constexpr size_t XT_OFF    = 0;                          // [R][B][I]
constexpr size_t XT_N      = (size_t)R_ * B_ * I_;       // 2,359,296
constexpr size_t SA_OFF    = XT_OFF + XT_N;              // [CO][B] raw s, iter 0/2
constexpr size_t SAB_N     = (size_t)CO_ * B_;           // 40,960
constexpr size_t SB_OFF    = SA_OFF + SAB_N;             // [CO][B] raw s, iter 1
constexpr size_t BIJ_OFF   = SB_OFF + SAB_N;             // [C][R]
constexpr size_t BIJ_N     = (size_t)C_ * R_;            // 11,520
constexpr size_t ZERO_N    = 2 * SAB_N + BIJ_N;          // 93,440 floats
constexpr size_t FL_TOTAL  = BIJ_OFF + BIJ_N;

__device__ __forceinline__ float squashf(float s) {
    // faithful to reference: s^2*s/((1+s^2)*sqrt(s^2)) == s*|s|/(1+s^2)
    return s * fabsf(s) / (1.0f + s * s);
}

// ===========================================================================
// k_tr: x[b,r,i] -> xT[r,b,i]; zero sA|sB|bij.  tile 8 b x 32 r.  grid 1152.
// ===========================================================================
__global__ __launch_bounds__(256) void k_tr(const float* __restrict__ x,
                                            float* __restrict__ xT,
                                            float* __restrict__ zbase) {
    __shared__ float t[8][32][8];
    const int tid = threadIdx.x;
    {
        const int gi = blockIdx.x * 256 + tid;
        if (gi < (int)(ZERO_N / 4))
            ((float4*)zbase)[gi] = make_float4(0.f, 0.f, 0.f, 0.f);
    }
    const int r0 = (blockIdx.x % 36) * 32;
    const int b0 = (blockIdx.x / 36) * 8;
    {
        const int rl = tid & 31, bl = tid >> 5;
        const float4* p = (const float4*)(x + ((size_t)(b0 + bl) * R_ + (r0 + rl)) * I_);
        const float4 a0 = p[0], a1 = p[1];
        float* d = &t[bl][rl][0];
        *(float4*)d = a0;
        *(float4*)(d + 4) = a1;
    }
    __syncthreads();
    {
        const int f = tid & 7, rw = tid >> 3;   // f = b-local
        const float* s8 = &t[f][rw][0];
        const float4 a0 = *(const float4*)s8, a1 = *(const float4*)(s8 + 4);
        float* d = xT + ((size_t)(r0 + rw) * B_ + (b0 + f)) * I_;
        *(float4*)d = a0;
        *(float4*)(d + 4) = a1;
    }
}

// ===========================================================================
// k_s7: s_dst[co][b] (+=, atomic) sum_{r in chunk} cw[r,c]*dot(W[r,c,o,:],xT[r,b,:])
// 1-D grid 1280: bid = c*128 + ks*4 + bq.  c-stride 128 == 0 (mod 8) keeps all
// 10 c-copies of an x-chunk on one XCD (L2 reuse).
// Softmax over routes computed per-block from bijT (redundant, ~90 VALU ops +
// 1152-float L2 read) -> no separate softmax launch, no cij buffer.
// v-phase folded in: 4 coalesced wave-atomicAdds per thread into s_dst
// (32-way per-line contention across ks-chunks -> cheap) -> no k_v4 launches.
// ===========================================================================
template <bool UNIFORM>
__global__ __launch_bounds__(256) void k_s7(const float* __restrict__ xT,
                                            const float* __restrict__ Wm,
                                            const float* __restrict__ bijT,
                                            float* __restrict__ s_dst) {
    __shared__ __align__(16) float wl[RC_ * 128];   // 18.4 KB
    __shared__ float cwch[RC_];
    __shared__ float sred[8];

    const int tid   = threadIdx.x;
    const int lane  = tid & 63;
    const int bid   = blockIdx.x;
    const int c     = bid >> 7;           // 0..9
    const int chunk = bid & 127;
    const int ks    = chunk >> 2;         // 0..31
    const int bq    = chunk & 3;          // 0..3
    const int r0    = ks * RC_;

    // ---- per-block softmax over routes for capsule c -> cwch[0..35] ----
    if (!UNIFORM) {
        const float* bc = bijT + (size_t)c * R_;
        float bv[5];
        float m = -1e30f;
        #pragma unroll
        for (int k = 0; k < 5; ++k) {
            const int r = tid + 256 * k;
            bv[k] = (r < R_) ? bc[r] : -1e30f;
            m = fmaxf(m, bv[k]);
        }
        #pragma unroll
        for (int off = 32; off > 0; off >>= 1)
            m = fmaxf(m, __shfl_down(m, off, 64));
        if (lane == 0) sred[tid >> 6] = m;
        __syncthreads();
        const float bm = fmaxf(fmaxf(sred[0], sred[1]), fmaxf(sred[2], sred[3]));
        float se = 0.f;
        #pragma unroll
        for (int k = 0; k < 5; ++k)
            se += (bv[k] > -1e29f) ? expf(bv[k] - bm) : 0.f;
        #pragma unroll
        for (int off = 32; off > 0; off >>= 1)
            se += __shfl_down(se, off, 64);
        if (lane == 0) sred[4 + (tid >> 6)] = se;
        __syncthreads();
        const float inv = 1.0f / (sred[4] + sred[5] + sred[6] + sred[7]);
        if (tid < RC_) cwch[tid] = expf(bc[r0 + tid] - bm) * inv;
        __syncthreads();
    }

    // ---- stage cw-scaled W chunk: 36 r x 32 f4 = 1152 f4 ----
    {
        const float4* src = (const float4*)(Wm + ((size_t)r0 * C_ + c) * 128);
        float4* dst = (float4*)wl;
        #pragma unroll
        for (int k = 0; k < (RC_ * 32 + 255) / 256; ++k) {
            const int idx = tid + 256 * k;
            if (idx < RC_ * 32) {
                const int r = idx >> 5, q = idx & 31;
                float4 wv = src[(size_t)r * (C_ * 32) + q];
                const float cw = UNIFORM ? (1.0f / (float)R_) : cwch[r];
                wv.x *= cw; wv.y *= cw; wv.z *= cw; wv.w *= cw;
                dst[idx] = wv;
            }
        }
    }
    __syncthreads();

    const int o0 = (tid >> 6) * 4;        // wave-uniform -> LDS broadcast reads
    const float* xbase = xT + ((size_t)r0 * B_ + bq * 64 + lane) * I_;

    float acc[4] = {0.f, 0.f, 0.f, 0.f};

    #pragma unroll 4
    for (int r = 0; r < RC_; ++r) {
        const float4* xp = (const float4*)(xbase + (size_t)r * B_ * I_);
        const float4 a0 = xp[0], a1 = xp[1];
        const float4* wp = (const float4*)&wl[r * 128 + o0 * 8];
        #pragma unroll
        for (int oo = 0; oo < 4; ++oo) {
            const float4 w0 = wp[oo * 2 + 0];
            const float4 w1 = wp[oo * 2 + 1];
            float a = acc[oo];
            a = fmaf(a0.x, w0.x, a);
            a = fmaf(a0.y, w0.y, a);
            a = fmaf(a0.z, w0.z, a);
            a = fmaf(a0.w, w0.w, a);
            a = fmaf(a1.x, w1.x, a);
            a = fmaf(a1.y, w1.y, a);
            a = fmaf(a1.z, w1.z, a);
            a = fmaf(a1.w, w1.w, a);
            acc[oo] = a;
        }
    }

    // s layout [co][b]: lanes (b) coalesce -> 4 coalesced wave-atomics
    float* sp = s_dst + (size_t)(c * O_ + o0) * B_ + bq * 64 + lane;
    #pragma unroll
    for (int oo = 0; oo < 4; ++oo)
        atomicAdd(sp + (size_t)oo * B_, acc[oo]);
}

// ===========================================================================
// k_a6: bijT[c, r0+rr] += (1/B) sum_o sum_i W[r,c,o,i]*(sum_b v[b,c,o]*xT[r,b,i])
// v = squash(s_read) applied on the fly (v never materialized).
// grid 576 blocks, 640 thr = 160 co x 4 b-groups of 64.
// v-reads batched x8 (two f4 loads in flight) -> fixes the latency-bound
// 64-serial-load chain seen in r4 counters (VALUBusy 5%).
// Blocks 0..39 also zero s_zero (buffer the NEXT s-launch accumulates into).
// Direct (non-atomic) bij store: block owns rows r0..r0+RT_-1.
// ===========================================================================
__global__ __launch_bounds__(640) void k_a6(const float* __restrict__ xT,
                                            const float* __restrict__ Wm,
                                            const float* __restrict__ s_read,
                                            float* __restrict__ s_zero,
                                            float* __restrict__ bijT) {
    __shared__ __align__(16) float xrow[RT_ * B_ * I_];   // 16 KB
    __shared__ float part[RT_][640];

    const int tid = threadIdx.x;
    const int r0  = blockIdx.x * RT_;

    if (s_zero != nullptr && blockIdx.x < 40 && tid < 256) {
        ((float4*)s_zero)[blockIdx.x * 256 + tid] =
            make_float4(0.f, 0.f, 0.f, 0.f);
    }

    for (int k = tid; k < RT_ * B_ * I_ / 4; k += 640)
        ((float4*)xrow)[k] = ((const float4*)(xT + (size_t)r0 * B_ * I_))[k];
    __syncthreads();

    const int co = tid % CO_;
    const int bg = tid / CO_;
    const int b0 = bg * 64;

    float acc[RT_][8];
    #pragma unroll
    for (int rr = 0; rr < RT_; ++rr)
        #pragma unroll
        for (int i = 0; i < 8; ++i) acc[rr][i] = 0.f;

    const float* vp = s_read + (size_t)co * B_ + b0;   // [co][b] layout
    #pragma unroll 1
    for (int bb = 0; bb < 64; bb += 8) {
        const float4 v0 = *(const float4*)(vp + bb);
        const float4 v1 = *(const float4*)(vp + bb + 4);
        float vt[8];
        vt[0] = squashf(v0.x); vt[1] = squashf(v0.y);
        vt[2] = squashf(v0.z); vt[3] = squashf(v0.w);
        vt[4] = squashf(v1.x); vt[5] = squashf(v1.y);
        vt[6] = squashf(v1.z); vt[7] = squashf(v1.w);
        #pragma unroll
        for (int j = 0; j < 8; ++j) {
            const int b = b0 + bb + j;
            #pragma unroll
            for (int rr = 0; rr < RT_; ++rr) {
                const float4 y0 = *(const float4*)(&xrow[(rr * B_ + b) * I_]);
                const float4 y1 = *(const float4*)(&xrow[(rr * B_ + b) * I_ + 4]);
                acc[rr][0] = fmaf(vt[j], y0.x, acc[rr][0]);
                acc[rr][1] = fmaf(vt[j], y0.y, acc[rr][1]);
                acc[rr][2] = fmaf(vt[j], y0.z, acc[rr][2]);
                acc[rr][3] = fmaf(vt[j], y0.w, acc[rr][3]);
                acc[rr][4] = fmaf(vt[j], y1.x, acc[rr][4]);
                acc[rr][5] = fmaf(vt[j], y1.y, acc[rr][5]);
                acc[rr][6] = fmaf(vt[j], y1.z, acc[rr][6]);
                acc[rr][7] = fmaf(vt[j], y1.w, acc[rr][7]);
            }
        }
    }

    #pragma unroll
    for (int rr = 0; rr < RT_; ++rr) {
        const float* wp = Wm + (((size_t)(r0 + rr)) * CO_ + co) * I_;
        const float4 w0 = *(const float4*)wp;
        const float4 w1 = *(const float4*)(wp + 4);
        const float p0 = fmaf(acc[rr][1], w0.y, acc[rr][0] * w0.x);
        const float p1 = fmaf(acc[rr][3], w0.w, acc[rr][2] * w0.z);
        const float p2 = fmaf(acc[rr][5], w1.y, acc[rr][4] * w1.x);
        const float p3 = fmaf(acc[rr][7], w1.w, acc[rr][6] * w1.z);
        part[rr][tid] = (p0 + p1) + (p2 + p3);
    }
    __syncthreads();

    if (tid < CO_) {
        #pragma unroll
        for (int rr = 0; rr < RT_; ++rr) {
            float a = part[rr][tid] + part[rr][CO_ + tid] +
                      part[rr][2 * CO_ + tid] + part[rr][3 * CO_ + tid];
            #pragma unroll
            for (int off = 8; off > 0; off >>= 1)
                a += __shfl_down(a, off, 16);
            if ((tid & 15) == 0)
                bijT[(size_t)(tid >> 4) * R_ + (r0 + rr)] += a * (1.0f / (float)B_);
        }
    }
}

// ===========================================================================
// k_sqout: out[b,co] = squash(s[co][b]).  grid 160 (=co), 256 thr (=b).
// ===========================================================================
__global__ __launch_bounds__(256) void k_sqout(const float* __restrict__ s,
                                               float* __restrict__ out) {
    const int co = blockIdx.x;
    const int b  = threadIdx.x;
    out[(size_t)b * CO_ + co] = squashf(s[(size_t)co * B_ + b]);
}

// ===========================================================================
// FALLBACK tier 3 (tiny ws)
// ===========================================================================
template <bool UNIFORM>
__global__ __launch_bounds__(256) void k_s_f(const float* __restrict__ x,
                                             const float* __restrict__ Wm,
                                             const float* __restrict__ cij,
                                             float* __restrict__ s_out) {
    const int o  = threadIdx.x & 15;
    const int tb = threadIdx.x >> 4;
    const int b  = blockIdx.z * MBF_ + tb;
    const int c  = blockIdx.y;
    const int r0 = blockIdx.x * RCF_;

    const float* xp = x + ((size_t)b * R_ + r0) * I_;
    const float* wp = Wm + (((size_t)r0 * C_ + c) * O_ + o) * I_;
    const float* cp = cij + (size_t)r0 * C_ + c;

    float acc = 0.f;
    #pragma unroll 4
    for (int r = 0; r < RCF_; ++r) {
        const float4 xv0 = *(const float4*)(xp);
        const float4 xv1 = *(const float4*)(xp + 4);
        const float4 wv0 = *(const float4*)(wp);
        const float4 wv1 = *(const float4*)(wp + 4);
        const float p0 = fmaf(xv0.y, wv0.y, xv0.x * wv0.x);
        const float p1 = fmaf(xv0.w, wv0.w, xv0.z * wv0.z);
        const float p2 = fmaf(xv1.y, wv1.y, xv1.x * wv1.x);
        const float p3 = fmaf(xv1.w, wv1.w, xv1.z * wv1.z);
        const float cw = UNIFORM ? (1.0f / (float)R_) : cp[0];
        acc = fmaf(cw, (p0 + p1) + (p2 + p3), acc);
        xp += I_;
        wp += WRI_;
        cp += C_;
    }
    atomicAdd(&s_out[((size_t)b * C_ + c) * O_ + o], acc);
}

__global__ __launch_bounds__(256) void k_a_f(const float* __restrict__ x,
                                             const float* __restrict__ Wm,
                                             const float* __restrict__ s_in,
                                             float* __restrict__ amean) {
    __shared__ __align__(16) float wlds[2 * WRI_];
    __shared__ float red[4][2 * C_];

    const int tid = threadIdx.x;
    const int r0  = blockIdx.x * 2;

    const float* wsrc = Wm + (size_t)r0 * WRI_;
    #pragma unroll
    for (int k = 0; k < 2 * WRI_ / 256; ++k)
        wlds[tid + 256 * k] = wsrc[tid + 256 * k];
    __syncthreads();

    const int b    = tid;
    const int lane = tid & 63;
    const int wv   = tid >> 6;

    float xv[2][I_];
    const float4* xp4 = (const float4*)(x + ((size_t)b * R_ + r0) * I_);
    #pragma unroll
    for (int rr = 0; rr < 2; ++rr) {
        const float4 a0 = xp4[rr * 2 + 0];
        const float4 a1 = xp4[rr * 2 + 1];
        xv[rr][0] = a0.x; xv[rr][1] = a0.y; xv[rr][2] = a0.z; xv[rr][3] = a0.w;
        xv[rr][4] = a1.x; xv[rr][5] = a1.y; xv[rr][6] = a1.z; xv[rr][7] = a1.w;
    }

    #pragma unroll 1
    for (int c = 0; c < C_; ++c) {
        const float4* sp4 = (const float4*)(s_in + ((size_t)b * C_ + c) * O_);
        float v[O_];
        #pragma unroll
        for (int q = 0; q < 4; ++q) {
            const float4 sv = sp4[q];
            v[q * 4 + 0] = squashf(sv.x);
            v[q * 4 + 1] = squashf(sv.y);
            v[q * 4 + 2] = squashf(sv.z);
            v[q * 4 + 3] = squashf(sv.w);
        }
        #pragma unroll 1
        for (int rr = 0; rr < 2; ++rr) {
            const float4* wl4 = (const float4*)&wlds[(rr * C_ + c) * O_ * I_];
            float a = 0.f;
            #pragma unroll
            for (int o = 0; o < O_; ++o) {
                const float4 w0 = wl4[o * 2 + 0];
                const float4 w1 = wl4[o * 2 + 1];
                float u = xv[rr][0] * w0.x;
                u = fmaf(xv[rr][1], w0.y, u);
                u = fmaf(xv[rr][2], w0.z, u);
                u = fmaf(xv[rr][3], w0.w, u);
                u = fmaf(xv[rr][4], w1.x, u);
                u = fmaf(xv[rr][5], w1.y, u);
                u = fmaf(xv[rr][6], w1.z, u);
                u = fmaf(xv[rr][7], w1.w, u);
                a = fmaf(u, v[o], a);
            }
            #pragma unroll
            for (int off = 32; off > 0; off >>= 1)
                a += __shfl_down(a, off, 64);
            if (lane == 0) red[wv][rr * C_ + c] = a;
        }
    }

    __syncthreads();
    if (tid < 2 * C_) {
        const float t = red[0][tid] + red[1][tid] + red[2][tid] + red[3][tid];
        const int rr = tid / C_;
        const int c  = tid % C_;
        amean[(size_t)(r0 + rr) * C_ + c] = t * (1.0f / (float)B_);
    }
}

__global__ __launch_bounds__(256) void k_soft(const float* __restrict__ amean,
                                              float* __restrict__ bij,
                                              float* __restrict__ cij) {
    const int c   = blockIdx.x;
    const int tid = threadIdx.x;
    __shared__ float sred[4];

    float vals[5];
    float m = -1e30f;
    #pragma unroll
    for (int k = 0; k < 5; ++k) {
        const int r = tid + 256 * k;
        if (r < R_) {
            const size_t idx = (size_t)r * C_ + c;
            const float vv = bij[idx] + amean[idx];
            bij[idx] = vv;
            vals[k] = vv;
            m = fmaxf(m, vv);
        } else {
            vals[k] = -1e30f;
        }
    }
    #pragma unroll
    for (int off = 32; off > 0; off >>= 1)
        m = fmaxf(m, __shfl_down(m, off, 64));
    if ((tid & 63) == 0) sred[tid >> 6] = m;
    __syncthreads();
    const float bm = fmaxf(fmaxf(sred[0], sred[1]), fmaxf(sred[2], sred[3]));
    __syncthreads();

    float se = 0.f;
    #pragma unroll
    for (int k = 0; k < 5; ++k)
        se += (vals[k] > -1e29f) ? expf(vals[k] - bm) : 0.f;
    #pragma unroll
    for (int off = 32; off > 0; off >>= 1)
        se += __shfl_down(se, off, 64);
    if ((tid & 63) == 0) sred[tid >> 6] = se;
    __syncthreads();
    const float inv = 1.0f / (sred[0] + sred[1] + sred[2] + sred[3]);

    #pragma unroll
    for (int k = 0; k < 5; ++k) {
        const int r = tid + 256 * k;
        if (r < R_) cij[(size_t)r * C_ + c] = expf(vals[k] - bm) * inv;
    }
}

__global__ __launch_bounds__(256) void k_squash(float* __restrict__ s) {
    const int idx = blockIdx.x * 256 + threadIdx.x;
    if (idx < B_ * CO_) s[idx] = squashf(s[idx]);
}

} // namespace

extern "C" void kernel_launch(void* const* d_in, const int* in_sizes, int n_in,
                              void* d_out, int out_size, void* d_ws, size_t ws_size,
                              hipStream_t stream) {
    const float* x  = (const float*)d_in[0];   // [256,1152,8]
    const float* Wm = (const float*)d_in[1];   // [1152,10,16,8]
    float* out = (float*)d_out;                // [256,10,16] flat = 40960
    float* ws  = (float*)d_ws;

    const size_t need = FL_TOTAL * sizeof(float);

    if (ws_size >= need) {
        // ---------------- main path: 7 nodes ----------------
        float* xT   = ws + XT_OFF;
        float* sA   = ws + SA_OFF;
        float* sB   = ws + SB_OFF;
        float* bijT = ws + BIJ_OFF;

        k_tr<<<1152, 256, 0, stream>>>(x, xT, sA /* = zbase, zeroes sA|sB|bij */);

        // iter 0 (uniform weights; softmax(0) == 1/R)
        k_s7<true><<<C_ * 128, 256, 0, stream>>>(xT, Wm, bijT, sA);
        k_a6<<<NA_, 640, 0, stream>>>(xT, Wm, sA, nullptr, bijT);

        // iter 1  (sB zeroed by k_tr)
        k_s7<false><<<C_ * 128, 256, 0, stream>>>(xT, Wm, bijT, sB);
        k_a6<<<NA_, 640, 0, stream>>>(xT, Wm, sB, sA /* zero for iter 2 */, bijT);

        // iter 2
        k_s7<false><<<C_ * 128, 256, 0, stream>>>(xT, Wm, bijT, sA);
        k_sqout<<<CO_, 256, 0, stream>>>(sA, out);
    } else {
        // ---------------- tier 3 ----------------
        float* s_buf = ws;
        float* cij   = ws + 40960;
        float* bij   = cij + R_ * C_;
        float* amean = bij + R_ * C_;

        const dim3 gsf(KSF_, C_, B_ / MBF_);

        hipMemsetAsync(bij, 0, R_ * C_ * sizeof(float), stream);

        hipMemsetAsync(s_buf, 0, B_ * CO_ * sizeof(float), stream);
        k_s_f<true><<<gsf, 256, 0, stream>>>(x, Wm, cij, s_buf);
        k_a_f<<<R_ / 2, 256, 0, stream>>>(x, Wm, s_buf, amean);
        k_soft<<<C_, 256, 0, stream>>>(amean, bij, cij);

        hipMemsetAsync(s_buf, 0, B_ * CO_ * sizeof(float), stream);
        k_s_f<false><<<gsf, 256, 0, stream>>>(x, Wm, cij, s_buf);
        k_a_f<<<R_ / 2, 256, 0, stream>>>(x, Wm, s_buf, amean);
        k_soft<<<C_, 256, 0, stream>>>(amean, bij, cij);

        hipMemsetAsync(out, 0, B_ * CO_ * sizeof(float), stream);
        k_s_f<false><<<gsf, 256, 0, stream>>>(x, Wm, cij, out);
        k_squash<<<(B_ * CO_ + 255) / 256, 256, 0, stream>>>(out);
    }
}